// Round 7
// baseline (138.606 us; speedup 1.0000x reference)
//
#include <hip/hip_runtime.h>
#include <hip/hip_bf16.h>

#define SEQ 14
#define IN 24
#define H 64
#define CLS 10
#define NBATCH 65536
#define WSCALE 2.0f   // exact power of 2: folds tanh's 2*v into weights/biases

typedef __attribute__((ext_vector_type(4))) float f32x4;
typedef __attribute__((ext_vector_type(8))) short bf16x8;
typedef __attribute__((ext_vector_type(4))) short bf16x4;

#define MFMA(A, B, C) __builtin_amdgcn_mfma_f32_16x16x32_bf16(A, B, C, 0, 0, 0)
// Anti-rematerialization pin (R5-verified).
#define PIN(v) asm volatile("" : "+v"(v))

static __device__ __forceinline__ short f2bf(float f) {
    __hip_bfloat16 h = __float2bfloat16(f);
    union { __hip_bfloat16 h; short s; } u; u.h = h;
    return u.s;
}
static __device__ __forceinline__ bf16x8 pack8(f32x4 a, f32x4 b) {
    bf16x8 r;
    r[0] = f2bf(a[0]); r[1] = f2bf(a[1]); r[2] = f2bf(a[2]); r[3] = f2bf(a[3]);
    r[4] = f2bf(b[0]); r[5] = f2bf(b[1]); r[6] = f2bf(b[2]); r[7] = f2bf(b[3]);
    return r;
}
static __device__ __forceinline__ bf16x8 loadw8(const float* p) {
    return pack8(*(const f32x4*)p, *(const f32x4*)(p + 4));
}
static __device__ __forceinline__ bf16x8 loadw8s(const float* p, float s) {
    f32x4 a = *(const f32x4*)p, b = *(const f32x4*)(p + 4);
    return pack8(a * s, b * s);
}
// y is already 2*v (weights prescaled): tanh(v) = 1 - 2/(e^y + 1)
static __device__ __forceinline__ float tanh2(float y) {
    float e = __expf(y);
    return fmaf(-2.0f, __builtin_amdgcn_rcpf(e + 1.0f), 1.0f);
}

// Layer-pipelined: 6 waves = 3 layers x 2 row-halves, 32 batch/block.
// Interval s: layer l computes t = s-l. One barrier per interval (16 total).
// All activations in double-buffered B-layout LDS X[par][layer][kg][col][8]:
//   write at s -> parity s&1; read at s -> parity (s-1)&1 (barrier-separated).
// Frag maps (R3-R6 HW-verified): A row-in-tile=c, k=32f+8g+j; B col=c batch,
// same k; D col=c, row-in-tile=4g+r.
__global__ __launch_bounds__(384, 4) void rnn_pipe(
    const float* __restrict__ x,     // [B, T, 24]
    const float* __restrict__ h0in,  // [3, B, 64]
    const float* __restrict__ pWi0, const float* __restrict__ pWh0,
    const float* __restrict__ pbi0, const float* __restrict__ pbh0,
    const float* __restrict__ pWi1, const float* __restrict__ pWh1,
    const float* __restrict__ pbi1, const float* __restrict__ pbh1,
    const float* __restrict__ pWi2, const float* __restrict__ pWh2,
    const float* __restrict__ pbi2, const float* __restrict__ pbh2,
    const float* __restrict__ pWout, const float* __restrict__ pbout,
    float* __restrict__ out)         // [B*10] ++ [3*B*64]
{
    __shared__ __align__(16) short X[2][3][8][32][8];  // 24.0 KB
    __shared__ float blds[3][H];

    const int tid  = threadIdx.x;
    const int lane = tid & 63;
    const int g    = lane >> 4;
    const int c    = lane & 15;
    const int wid  = tid >> 6;
    const int l    = wid >> 1;       // layer 0..2 (wave-uniform)
    const int u    = wid & 1;        // row-half 0..1
    const int b0   = blockIdx.x * 32;

    // ---- preload h0 -> X[(l+1)&1][l] (B-layout bf16); biases (scaled) ----
    for (int sl = tid; sl < 768; sl += 384) {
        const int ll = sl >> 8, rem = sl & 255, kg = rem >> 5, col = rem & 31;
        const float* p = h0in + ((size_t)ll * NBATCH + b0 + col) * H + kg * 8;
        *(bf16x8*)&X[(ll + 1) & 1][ll][kg][col][0] =
            pack8(*(const f32x4*)p, *(const f32x4*)(p + 4));
    }
    if (tid < 192) {
        const int ll = tid >> 6, j = tid & 63;
        const float* bi = ll == 0 ? pbi0 : ll == 1 ? pbi1 : pbi2;
        const float* bh = ll == 0 ? pbh0 : ll == 1 ? pbh1 : pbh2;
        blds[ll][j] = WSCALE * (bi[j] + bh[j]);
    }

    // ---- this wave's weights (32 VGPR, prescaled, pinned) ----
    const float* Whp = l == 0 ? pWh0 : l == 1 ? pWh1 : pWh2;
    const float* Wip = l == 0 ? pWi0 : l == 1 ? pWi1 : pWi2;
    bf16x8 aWh[2][2], aWi[2][2];
#pragma unroll
    for (int m = 0; m < 2; ++m) {
        const int row = 32 * u + 16 * m + c;
#pragma unroll
        for (int f = 0; f < 2; ++f) {
            aWh[m][f] = loadw8s(Whp + row * H + 32 * f + 8 * g, WSCALE);
            PIN(aWh[m][f]);
        }
        if (l == 0) {
            bf16x8 w;
#pragma unroll
            for (int j = 0; j < 8; ++j) w[j] = 0;
            if (g < 3) w = loadw8s(Wip + row * IN + 8 * g, WSCALE);
            aWi[m][0] = w; PIN(aWi[m][0]);
#pragma unroll
            for (int j = 0; j < 8; ++j) aWi[m][1][j] = 0;
        } else {
#pragma unroll
            for (int f = 0; f < 2; ++f) {
                aWi[m][f] = loadw8s(Wip + row * H + 32 * f + 8 * g, WSCALE);
                PIN(aWi[m][f]);
            }
        }
    }

    float* hsout = out + (size_t)NBATCH * CLS;
    __syncthreads();

#pragma unroll 1
    for (int s = 0; s < SEQ + 2; ++s) {
        const int rpar = (s & 1) ^ 1, wpar = s & 1;
        if (s >= l && s - l < SEQ) {          // wave-uniform
            const int t = s - l;
            // self B-frags (own output at t-1, or preloaded h0)
            bf16x8 sf0a = *(const bf16x8*)&X[rpar][l][g][c][0];
            bf16x8 sf0b = *(const bf16x8*)&X[rpar][l][g][c + 16][0];
            bf16x8 sf1a = *(const bf16x8*)&X[rpar][l][4 + g][c][0];
            bf16x8 sf1b = *(const bf16x8*)&X[rpar][l][4 + g][c + 16][0];
            // input B-frags (x for L0; layer-below output at same t otherwise)
            bf16x8 if0a, if0b, if1a, if1b;
            if (l == 0) {
#pragma unroll
                for (int j = 0; j < 8; ++j) { if0a[j] = 0; if0b[j] = 0; if1a[j] = 0; if1b[j] = 0; }
                if (g < 3) {
                    const float* xp0 = x + ((size_t)(b0 + c) * SEQ + t) * IN + 8 * g;
                    const float* xp1 = x + ((size_t)(b0 + 16 + c) * SEQ + t) * IN + 8 * g;
                    if0a = pack8(*(const f32x4*)xp0, *(const f32x4*)(xp0 + 4));
                    if0b = pack8(*(const f32x4*)xp1, *(const f32x4*)(xp1 + 4));
                }
            } else {
                if0a = *(const bf16x8*)&X[rpar][l - 1][g][c][0];
                if0b = *(const bf16x8*)&X[rpar][l - 1][g][c + 16][0];
                if1a = *(const bf16x8*)&X[rpar][l - 1][4 + g][c][0];
                if1b = *(const bf16x8*)&X[rpar][l - 1][4 + g][c + 16][0];
            }
#pragma unroll
            for (int m = 0; m < 2; ++m) {
                const int rbase = 32 * u + 16 * m;
                f32x4 bv = *(const f32x4*)&blds[l][rbase + 4 * g];
                // ---- n-tile 0 ----
                {
                    f32x4 acc = {0.f, 0.f, 0.f, 0.f};
                    acc = MFMA(aWh[m][0], sf0a, acc);
                    acc = MFMA(aWh[m][1], sf1a, acc);
                    acc = MFMA(aWi[m][0], if0a, acc);
                    if (l) acc = MFMA(aWi[m][1], if1a, acc);
                    f32x4 th;
#pragma unroll
                    for (int r = 0; r < 4; ++r) th[r] = tanh2(acc[r] + bv[r]);
                    if (t == SEQ - 1)
                        *(f32x4*)(hsout + (size_t)l * NBATCH * H +
                                  (size_t)(b0 + c) * H + rbase + 4 * g) = th;
                    bf16x4 pv;
#pragma unroll
                    for (int r = 0; r < 4; ++r) pv[r] = f2bf(th[r]);
                    *(bf16x4*)&X[wpar][l][4 * u + 2 * m + (g >> 1)][c][4 * (g & 1)] = pv;
                }
                // ---- n-tile 1 ----
                {
                    f32x4 acc = {0.f, 0.f, 0.f, 0.f};
                    acc = MFMA(aWh[m][0], sf0b, acc);
                    acc = MFMA(aWh[m][1], sf1b, acc);
                    acc = MFMA(aWi[m][0], if0b, acc);
                    if (l) acc = MFMA(aWi[m][1], if1b, acc);
                    f32x4 th;
#pragma unroll
                    for (int r = 0; r < 4; ++r) th[r] = tanh2(acc[r] + bv[r]);
                    if (t == SEQ - 1)
                        *(f32x4*)(hsout + (size_t)l * NBATCH * H +
                                  (size_t)(b0 + 16 + c) * H + rbase + 4 * g) = th;
                    bf16x4 pv;
#pragma unroll
                    for (int r = 0; r < 4; ++r) pv[r] = f2bf(th[r]);
                    *(bf16x4*)&X[wpar][l][4 * u + 2 * m + (g >> 1)][c + 16][4 * (g & 1)] = pv;
                }
            }
        }
        __syncthreads();
    }

    // ---- logits head: wid 0. Final h2 = X[(SEQ+1)&1][2] (written at s=15). ----
    if (wid == 0) {
        const int fpar = (SEQ + 1) & 1;
        bf16x8 aWo0, aWo1;
#pragma unroll
        for (int j = 0; j < 8; ++j) { aWo0[j] = 0; aWo1[j] = 0; }
        if (c < CLS) {
            aWo0 = loadw8(pWout + c * H + 8 * g);
            aWo1 = loadw8(pWout + c * H + 32 + 8 * g);
        }
#pragma unroll
        for (int nt = 0; nt < 2; ++nt) {
            const int col = c + 16 * nt;
            bf16x8 s0 = *(const bf16x8*)&X[fpar][2][g][col][0];
            bf16x8 s1 = *(const bf16x8*)&X[fpar][2][4 + g][col][0];
            f32x4 acc = {0.f, 0.f, 0.f, 0.f};
            acc = MFMA(aWo0, s0, acc);
            acc = MFMA(aWo1, s1, acc);
#pragma unroll
            for (int r = 0; r < 4; ++r) {
                const int cls = 4 * g + r;
                if (cls < CLS)
                    out[(size_t)(b0 + col) * CLS + cls] = acc[r] + pbout[cls];
            }
        }
    }
}

extern "C" void kernel_launch(void* const* d_in, const int* in_sizes, int n_in,
                              void* d_out, int out_size, void* d_ws, size_t ws_size,
                              hipStream_t stream) {
    const float* x    = (const float*)d_in[0];
    const float* h0in = (const float*)d_in[1];
    const float* Wi0  = (const float*)d_in[2];
    const float* Wh0  = (const float*)d_in[3];
    const float* bi0  = (const float*)d_in[4];
    const float* bh0  = (const float*)d_in[5];
    const float* Wi1  = (const float*)d_in[6];
    const float* Wh1  = (const float*)d_in[7];
    const float* bi1  = (const float*)d_in[8];
    const float* bh1  = (const float*)d_in[9];
    const float* Wi2  = (const float*)d_in[10];
    const float* Wh2  = (const float*)d_in[11];
    const float* bi2  = (const float*)d_in[12];
    const float* bh2  = (const float*)d_in[13];
    const float* Wout = (const float*)d_in[14];
    const float* bout = (const float*)d_in[15];
    float* out = (float*)d_out;

    dim3 grid(NBATCH / 32), block(384);
    rnn_pipe<<<grid, block, 0, stream>>>(x, h0in, Wi0, Wh0, bi0, bh0,
                                         Wi1, Wh1, bi1, bh1,
                                         Wi2, Wh2, bi2, bh2,
                                         Wout, bout, out);
}

// Round 8
// 125.231 us; speedup vs baseline: 1.1068x; 1.1068x over previous
//
#include <hip/hip_runtime.h>
#include <hip/hip_bf16.h>

#define SEQ 14
#define IN 24
#define H 64
#define CLS 10
#define NBATCH 65536
#define NB 64   // batch elems per block
// 2*log2(e): folds BOTH the tanh 2*v and exp->exp2 conversion into the
// weight/bias prescale (applied in f32 BEFORE bf16 rounding: no extra error).
#define WSCALE 2.8853900817779268f

typedef __attribute__((ext_vector_type(4))) float f32x4;
typedef __attribute__((ext_vector_type(8))) short bf16x8;
typedef __attribute__((ext_vector_type(4))) short bf16x4;

#define MFMA(A, B, C) __builtin_amdgcn_mfma_f32_16x16x32_bf16(A, B, C, 0, 0, 0)
// Anti-rematerialization pin (R5-verified: stops weight re-loads in t-loop).
#define PIN(v) asm volatile("" : "+v"(v))

static __device__ __forceinline__ float fexp2(float x) {
#if __has_builtin(__builtin_amdgcn_exp2f)
    return __builtin_amdgcn_exp2f(x);   // v_exp_f32 (computes 2^x)
#else
    return __expf(x * 0.6931471805599453f);
#endif
}
// y = 2*v*log2(e) (prescaled weights): tanh(v) = 1 - 2/(2^y + 1)
static __device__ __forceinline__ float tanh2(float y) {
    float e = fexp2(y);
    return fmaf(-2.0f, __builtin_amdgcn_rcpf(e + 1.0f), 1.0f);
}
static __device__ __forceinline__ short f2bf(float f) {
    __hip_bfloat16 h = __float2bfloat16(f);
    union { __hip_bfloat16 h; short s; } u; u.h = h;
    return u.s;
}
static __device__ __forceinline__ bf16x8 pack8(f32x4 a, f32x4 b) {
    bf16x8 r;
    r[0] = f2bf(a[0]); r[1] = f2bf(a[1]); r[2] = f2bf(a[2]); r[3] = f2bf(a[3]);
    r[4] = f2bf(b[0]); r[5] = f2bf(b[1]); r[6] = f2bf(b[2]); r[7] = f2bf(b[3]);
    return r;
}
static __device__ __forceinline__ bf16x8 loadw8(const float* p) {
    return pack8(*(const f32x4*)p, *(const f32x4*)(p + 4));
}
static __device__ __forceinline__ bf16x8 loadw8s(const float* p, float s) {
    f32x4 a = *(const f32x4*)p, b = *(const f32x4*)(p + 4);
    return pack8(a * s, b * s);
}

// R5 structure widened to NB=64: WG = 256 thr = 4 waves, 64 batch elems.
// wave = m-tile (16 i-rows), 4 n-tiles each. Same 42 barriers, 2x work each.
// A = weights (VGPR, bf16, prescaled by WSCALE, PINned);
// B = activations (LDS, bf16); D = preact*WSCALE (f32); acc init = bias.
// Frag maps (R3-R7 HW-verified): A row=c, k=32f+8g+j; B col=c, same k;
// D col=c, row=4g+r. D->B repack: kg=2mt+(g>>1), e=4(g&1)+r.
__global__ __launch_bounds__(256, 3) void rnn_mfma(
    const float* __restrict__ x,     // [B, T, 24]
    const float* __restrict__ h0in,  // [3, B, 64]
    const float* __restrict__ pWi0, const float* __restrict__ pWh0,
    const float* __restrict__ pbi0, const float* __restrict__ pbh0,
    const float* __restrict__ pWi1, const float* __restrict__ pWh1,
    const float* __restrict__ pbi1, const float* __restrict__ pbh1,
    const float* __restrict__ pWi2, const float* __restrict__ pWh2,
    const float* __restrict__ pbi2, const float* __restrict__ pbh2,
    const float* __restrict__ pWout, const float* __restrict__ pbout,
    float* __restrict__ out)         // [B*10] ++ [3*B*64]
{
    __shared__ __align__(16) short hbuf[2][3][8][NB][8];  // 48 KB

    const int tid  = threadIdx.x;
    const int lane = tid & 63;
    const int g    = lane >> 4;      // k-group 0..3
    const int c    = lane & 15;      // col-in-n-tile / A-row-in-tile
    const int mt   = tid >> 6;       // wave id = m-tile 0..3
    const int b0   = blockIdx.x * NB;

    // ---- init hbuf parity 0 from h0 (bf16) ----
    for (int sl = tid; sl < 3 * 8 * NB; sl += 256) {
        const int ll = sl >> 9, rem = sl & 511, kg = rem >> 6, col = rem & 63;
        const float* p = h0in + ((size_t)ll * NBATCH + b0 + col) * H + kg * 8;
        *(bf16x8*)&hbuf[0][ll][kg][col][0] =
            pack8(*(const f32x4*)p, *(const f32x4*)(p + 4));
    }

    // ---- weight A-fragments (bf16, prescaled, pinned) ----
    const int ia = mt * 16 + c;
    bf16x8 aWi0;
    if (g < 3) aWi0 = loadw8s(pWi0 + ia * IN + g * 8, WSCALE);
    else {
#pragma unroll
        for (int j = 0; j < 8; ++j) aWi0[j] = 0;   // k = 24..31 zero pad
    }
    PIN(aWi0);
    bf16x8 aWh0[2], aWi1[2], aWh1[2], aWi2[2], aWh2[2];
#pragma unroll
    for (int kt = 0; kt < 2; ++kt) {
        aWh0[kt] = loadw8s(pWh0 + ia * H + kt * 32 + g * 8, WSCALE);  PIN(aWh0[kt]);
        aWi1[kt] = loadw8s(pWi1 + ia * H + kt * 32 + g * 8, WSCALE);  PIN(aWi1[kt]);
        aWh1[kt] = loadw8s(pWh1 + ia * H + kt * 32 + g * 8, WSCALE);  PIN(aWh1[kt]);
        aWi2[kt] = loadw8s(pWi2 + ia * H + kt * 32 + g * 8, WSCALE);  PIN(aWi2[kt]);
        aWh2[kt] = loadw8s(pWh2 + ia * H + kt * 32 + g * 8, WSCALE);  PIN(aWh2[kt]);
    }

    // ---- scaled bias per D-row (acc-init vectors), pinned ----
    const int i0 = mt * 16 + g * 4;
    f32x4 bs0 = (*(const f32x4*)(pbi0 + i0) + *(const f32x4*)(pbh0 + i0)) * WSCALE;
    f32x4 bs1 = (*(const f32x4*)(pbi1 + i0) + *(const f32x4*)(pbh1 + i0)) * WSCALE;
    f32x4 bs2 = (*(const f32x4*)(pbi2 + i0) + *(const f32x4*)(pbh2 + i0)) * WSCALE;
    PIN(bs0); PIN(bs1); PIN(bs2);

    const int kgw = mt * 2 + (g >> 1);   // repack write kg
    const int eb  = (g & 1) * 4;         // repack write elem base

    float* hsout = out + (size_t)NBATCH * CLS;

    __syncthreads();

#pragma unroll 1
    for (int t = 0; t < SEQ; ++t) {
        const int p = t & 1, q = p ^ 1;
        // ======== L0: below = x (global), self = hbuf[p][0] -> hbuf[q][0]
        {
#pragma unroll
            for (int nt = 0; nt < 4; ++nt) {
                const int col = c + 16 * nt;
                bf16x8 xB;
#pragma unroll
                for (int j = 0; j < 8; ++j) xB[j] = 0;
                if (g < 3) {
                    const float* xp = x + ((size_t)(b0 + col) * SEQ + t) * IN + 8 * g;
                    xB = pack8(*(const f32x4*)xp, *(const f32x4*)(xp + 4));
                }
                bf16x8 s0 = *(const bf16x8*)&hbuf[p][0][g][col][0];
                bf16x8 s1 = *(const bf16x8*)&hbuf[p][0][4 + g][col][0];
                f32x4 acc = bs0;                 // bias as C-init
                acc = MFMA(aWh0[0], s0, acc);
                acc = MFMA(aWh0[1], s1, acc);
                acc = MFMA(aWi0, xB, acc);
                f32x4 th;
#pragma unroll
                for (int r = 0; r < 4; ++r) th[r] = tanh2(acc[r]);
                if (t == SEQ - 1)
                    *(f32x4*)(hsout + (size_t)(b0 + col) * H + i0) = th;
                bf16x4 pv;
#pragma unroll
                for (int r = 0; r < 4; ++r) pv[r] = f2bf(th[r]);
                *(bf16x4*)&hbuf[q][0][kgw][col][eb] = pv;
            }
            __syncthreads();
        }
        // ======== L1 / L2 ========
#define LAYER12(li, bsv, aWhX, aWiX)                                            \
        {                                                                       \
            _Pragma("unroll")                                                   \
            for (int nt = 0; nt < 4; ++nt) {                                    \
                const int col = c + 16 * nt;                                    \
                bf16x8 s0 = *(const bf16x8*)&hbuf[p][li][g][col][0];            \
                bf16x8 s1 = *(const bf16x8*)&hbuf[p][li][4 + g][col][0];        \
                bf16x8 u0 = *(const bf16x8*)&hbuf[q][li - 1][g][col][0];        \
                bf16x8 u1 = *(const bf16x8*)&hbuf[q][li - 1][4 + g][col][0];    \
                f32x4 acc = bsv;                                                \
                acc = MFMA(aWhX[0], s0, acc);                                   \
                acc = MFMA(aWhX[1], s1, acc);                                   \
                acc = MFMA(aWiX[0], u0, acc);                                   \
                acc = MFMA(aWiX[1], u1, acc);                                   \
                f32x4 th;                                                       \
                _Pragma("unroll")                                               \
                for (int r = 0; r < 4; ++r) th[r] = tanh2(acc[r]);              \
                if (t == SEQ - 1)                                               \
                    *(f32x4*)(hsout + (size_t)(li) * NBATCH * H +               \
                              (size_t)(b0 + col) * H + i0) = th;                \
                bf16x4 pv;                                                      \
                _Pragma("unroll")                                               \
                for (int r = 0; r < 4; ++r) pv[r] = f2bf(th[r]);                \
                *(bf16x4*)&hbuf[q][li][kgw][col][eb] = pv;                      \
            }                                                                   \
            __syncthreads();                                                    \
        }
        LAYER12(1, bs1, aWh1, aWi1)
        LAYER12(2, bs2, aWh2, aWi2)
#undef LAYER12
    }

    // ===== logits head: wave mt -> cols [16mt, 16mt+16). Final h2 parity 0.
    {
        bf16x8 aWo0, aWo1;
#pragma unroll
        for (int j = 0; j < 8; ++j) { aWo0[j] = 0; aWo1[j] = 0; }
        if (c < CLS) {
            aWo0 = loadw8(pWout + c * H + 8 * g);         // unscaled: no tanh
            aWo1 = loadw8(pWout + c * H + 32 + 8 * g);
        }
        const int col = c + 16 * mt;
        bf16x8 s0 = *(const bf16x8*)&hbuf[0][2][g][col][0];
        bf16x8 s1 = *(const bf16x8*)&hbuf[0][2][4 + g][col][0];
        f32x4 acc = {0.f, 0.f, 0.f, 0.f};
        acc = MFMA(aWo0, s0, acc);
        acc = MFMA(aWo1, s1, acc);
#pragma unroll
        for (int r = 0; r < 4; ++r) {
            const int cls = 4 * g + r;
            if (cls < CLS)
                out[(size_t)(b0 + col) * CLS + cls] = acc[r] + pbout[cls];
        }
    }
}

extern "C" void kernel_launch(void* const* d_in, const int* in_sizes, int n_in,
                              void* d_out, int out_size, void* d_ws, size_t ws_size,
                              hipStream_t stream) {
    const float* x    = (const float*)d_in[0];
    const float* h0in = (const float*)d_in[1];
    const float* Wi0  = (const float*)d_in[2];
    const float* Wh0  = (const float*)d_in[3];
    const float* bi0  = (const float*)d_in[4];
    const float* bh0  = (const float*)d_in[5];
    const float* Wi1  = (const float*)d_in[6];
    const float* Wh1  = (const float*)d_in[7];
    const float* bi1  = (const float*)d_in[8];
    const float* bh1  = (const float*)d_in[9];
    const float* Wi2  = (const float*)d_in[10];
    const float* Wh2  = (const float*)d_in[11];
    const float* bi2  = (const float*)d_in[12];
    const float* bh2  = (const float*)d_in[13];
    const float* Wout = (const float*)d_in[14];
    const float* bout = (const float*)d_in[15];
    float* out = (float*)d_out;

    dim3 grid(NBATCH / NB), block(256);
    rnn_mfma<<<grid, block, 0, stream>>>(x, h0in, Wi0, Wh0, bi0, bh0,
                                         Wi1, Wh1, bi1, bh1,
                                         Wi2, Wh2, bi2, bh2,
                                         Wout, bout, out);
}